// Round 9
// baseline (447.877 us; speedup 1.0000x reference)
//
#include <hip/hip_runtime.h>

// Brute N^2 neighborlist (upper-triangular pairs), N=6000, P=17,997,000.
// Output layout (flat f32): [0,P) i | [P,2P) j | [2P,3P) d | [3P,6P) r_xyz.
//
// Session facts: kernel K ~= 100us across NT/plain, tiled/persistent,
// store placement (R3/R6/R7/R11); write floor 69us (432MB @ fill's 6.2TB/s);
// traffic byte-ideal (R9: WRITE 4x432MB, FETCH ~pos only), VALUBusy 28%,
// Occ 64-77%. Gap = store-issue duty cycle (H2) or HBM scatter limit (H3).
// R12 (this round, tests H2): every __syncthreads() compiles to
// s_waitcnt vmcnt(0) lgkmcnt(0) + s_barrier — in the persistent loop each
// wave drains ALL its previous-tile global stores at the loop-top barrier,
// gating store flow. Replace the 2 syncthreads/tile with ONE raw s_barrier
// preceded only by lgkmcnt(0) (m201 plain-HIP pattern); global stores stay
// in flight across barriers (s_endpgm drains at kernel end). LDS r-buffer
// double-buffered: compute tile k+1 into buf^1 while r of tile k streams
// out of buf. Safety: wave-own lgkmcnt(0) at barrier k+1 drains its
// ds_reads@k before any wave writes buf@k+2; buffers alternate.
// PBC wrap replicates numpy remainder bitwise (Sterbenz-exact branches);
// _rn intrinsics forbid contraction so the d<=0.5 mask cannot flip vs numpy.

constexpr int NPART  = 6000;
constexpr int NPAIRS = 17997000;     // N*(N-1)/2; % 1024 == 200, % 4 == 0
constexpr float CUT  = 0.5f;
constexpr int TPB = 256;
constexpr int PPT = 4;               // pairs per thread
constexpr int PPB = TPB * PPT;       // 1024 pairs per block
constexpr int NTILES = (NPAIRS + PPB - 1) / PPB;   // 17,576
constexpr int PERSIST_BLOCKS = 2048; // 256 CU x 8 blocks

typedef float fvec4 __attribute__((ext_vector_type(4)));

__device__ __forceinline__ int row_start(int i) {
    // pairs before row i: S(i) = i*(N-1) - i*(i-1)/2  (fits int32)
    return i * (NPART - 1) - (i * (i - 1)) / 2;
}

// numpy remainder(r+h, b) - h for |r| < b, b > 0, h = b/2 — bitwise-exact.
__device__ __forceinline__ float pbc_wrap(float r, float b, float h) {
    float v = __fadd_rn(r, h);
    if (v >= b)       v = __fsub_rn(v, b);
    else if (v < 0.f) v = __fadd_rn(v, b);
    return __fsub_rn(v, h);
}

__global__ __launch_bounds__(TPB) void nbl_kernel(
    const float* __restrict__ pos,     // [N,3]
    const float* __restrict__ boxv,    // [3,3]
    const int*  __restrict__ is_per,
    float* __restrict__ out)
{
    // double-buffered r staging: 2 x 12,288 B. 160KB/24.6KB -> 6 blocks/CU
    // (24 waves/CU), close to R11's effective occupancy.
    __shared__ float lds_r[2][PPB * 3];

    const int t = threadIdx.x;
    int buf = 0;

    #pragma unroll 1
    for (int tile = blockIdx.x; tile < NTILES; tile += gridDim.x, buf ^= 1) {
        const int pbase = tile * PPB;
        const int p     = pbase + t * PPT;
        // nvalid is 1024 or 200 — always % 4 == 0, so each thread's 4 pairs
        // are entirely valid or entirely invalid.
        const int nvalid = (NPAIRS - pbase < PPB) ? (NPAIRS - pbase) : PPB;
        const bool active = (t * PPT < nvalid);

        if (active) {
            // invert triangular index (fp32 estimate + int fixup)
            const float A = 2.0f * NPART - 1.0f;   // 11999
            float disc = A * A - 8.0f * (float)p;
            int i = (int)((A - sqrtf(disc)) * 0.5f);
            if (i < 0) i = 0;
            if (i > NPART - 2) i = NPART - 2;
            while (i < NPART - 2 && row_start(i + 1) <= p) ++i;
            while (i > 0 && row_start(i) > p) --i;
            int j = i + 1 + (p - row_start(i));

            const bool per = (*is_per != 0);
            const float bx = boxv[0], by = boxv[4], bz = boxv[8];
            const float hx = __fmul_rn(bx, 0.5f);
            const float hy = __fmul_rn(by, 0.5f);
            const float hz = __fmul_rn(bz, 0.5f);

            float oi[4], oj[4], od[4], orr[12];

            if (j + PPT - 1 < NPART) {
                // FAST PATH (99.87%): rows j..j+3 are 48 contiguous bytes.
                // Max read: j=5996 -> byte 72000 == end of pos, in bounds.
                const float xi = pos[3 * i + 0];
                const float yi = pos[3 * i + 1];
                const float zi = pos[3 * i + 2];
                fvec4 va, vb, vc;
                __builtin_memcpy(&va, pos + 3 * j + 0, 16);  // jx jy jz  j1x
                __builtin_memcpy(&vb, pos + 3 * j + 4, 16);  // j1y j1z j2x j2y
                __builtin_memcpy(&vc, pos + 3 * j + 8, 16);  // j2z j3x j3y j3z
                const float xj[4] = {va.x, va.w, vb.z, vc.y};
                const float yj[4] = {va.y, vb.x, vb.w, vc.z};
                const float zj[4] = {va.z, vb.y, vc.x, vc.w};
                const float fi = (float)i;

                #pragma unroll
                for (int k = 0; k < 4; ++k) {
                    float rx = __fsub_rn(xi, xj[k]);
                    float ry = __fsub_rn(yi, yj[k]);
                    float rz = __fsub_rn(zi, zj[k]);
                    if (per) {
                        rx = pbc_wrap(rx, bx, hx);
                        ry = pbc_wrap(ry, by, hy);
                        rz = pbc_wrap(rz, bz, hz);
                    }
                    float s = __fadd_rn(__fadd_rn(__fmul_rn(rx, rx), __fmul_rn(ry, ry)),
                                        __fmul_rn(rz, rz));
                    float d = __fsqrt_rn(s);
                    bool in = (d <= CUT);

                    oi[k] = in ? fi : -1.0f;
                    oj[k] = in ? (float)(j + k) : -1.0f;
                    od[k] = in ? d : 0.0f;
                    orr[3 * k + 0] = in ? rx : 0.0f;
                    orr[3 * k + 1] = in ? ry : 0.0f;
                    orr[3 * k + 2] = in ? rz : 0.0f;
                }
            } else {
                // SLOW PATH: row wrap inside the 4-pair group.
                float xi = pos[3 * i + 0], yi = pos[3 * i + 1], zi = pos[3 * i + 2];
                #pragma unroll
                for (int k = 0; k < 4; ++k) {
                    float xj = pos[3 * j + 0], yj = pos[3 * j + 1], zj = pos[3 * j + 2];
                    float rx = __fsub_rn(xi, xj);
                    float ry = __fsub_rn(yi, yj);
                    float rz = __fsub_rn(zi, zj);
                    if (per) {
                        rx = pbc_wrap(rx, bx, hx);
                        ry = pbc_wrap(ry, by, hy);
                        rz = pbc_wrap(rz, bz, hz);
                    }
                    float s = __fadd_rn(__fadd_rn(__fmul_rn(rx, rx), __fmul_rn(ry, ry)),
                                        __fmul_rn(rz, rz));
                    float d = __fsqrt_rn(s);
                    bool in = (d <= CUT);

                    oi[k] = in ? (float)i : -1.0f;
                    oj[k] = in ? (float)j : -1.0f;
                    od[k] = in ? d : 0.0f;
                    orr[3 * k + 0] = in ? rx : 0.0f;
                    orr[3 * k + 1] = in ? ry : 0.0f;
                    orr[3 * k + 2] = in ? rz : 0.0f;

                    ++j;
                    if (j == NPART) { ++i; j = i + 1;
                        xi = pos[3 * i + 0]; yi = pos[3 * i + 1]; zi = pos[3 * i + 2]; }
                }
            }

            // stage r-triples into this tile's buffer (16B-aligned b128 writes)
            fvec4* lv = (fvec4*)(lds_r[buf] + 12 * t);
            lv[0] = (fvec4){orr[0], orr[1], orr[2],  orr[3]};
            lv[1] = (fvec4){orr[4], orr[5], orr[6],  orr[7]};
            lv[2] = (fvec4){orr[8], orr[9], orr[10], orr[11]};

            // i/j/d stores: register-sourced, no barrier dependence — issue
            // now so they flow during the LDS phase. Plain stores (L2 path).
            *(fvec4*)(out + p)              = (fvec4){oi[0], oi[1], oi[2], oi[3]};
            *(fvec4*)(out + NPAIRS + p)     = (fvec4){oj[0], oj[1], oj[2], oj[3]};
            *(fvec4*)(out + 2 * NPAIRS + p) = (fvec4){od[0], od[1], od[2], od[3]};
        }

        // LDS-visibility barrier WITHOUT the vmcnt(0) drain __syncthreads
        // would emit: global stores from this and previous tiles remain in
        // flight. lgkmcnt(0) makes our ds_writes visible (and drains our
        // previous-tile ds_reads, guarding buf reuse two tiles out).
        asm volatile("s_waitcnt lgkmcnt(0)" ::: "memory");
        __builtin_amdgcn_s_barrier();

        // stream r of THIS tile out lane-contiguously while the next
        // iteration computes into the other buffer.
        const int nf4 = (3 * nvalid) / 4;                 // 768 or 150
        fvec4* rdst = (fvec4*)(out + 3 * NPAIRS + 3 * pbase);
        const fvec4* rsrc = (const fvec4*)lds_r[buf];
        #pragma unroll
        for (int s = 0; s < 3; ++s) {
            int q = t + TPB * s;
            if (q < nf4) rdst[q] = rsrc[q];
        }
    }
}

extern "C" void kernel_launch(void* const* d_in, const int* in_sizes, int n_in,
                              void* d_out, int out_size, void* d_ws, size_t ws_size,
                              hipStream_t stream) {
    const float* pos    = (const float*)d_in[0];
    const float* boxv   = (const float*)d_in[1];
    const int*   is_per = (const int*)d_in[2];
    float* out = (float*)d_out;

    nbl_kernel<<<PERSIST_BLOCKS, TPB, 0, stream>>>(pos, boxv, is_per, out);
}